// Round 1
// baseline (2264.342 us; speedup 1.0000x reference)
//
#include <hip/hip_runtime.h>
#include <cstdint>

namespace {
constexpr int H_  = 1536;
constexpr int NH_ = 24;
constexpr int HD_ = 64;
constexpr int B_  = 2;
constexpr int S_  = 2048;
constexpr int M_  = B_ * S_;   // 4096
}

union F4 { float4 v; float f[4]; };

// ---------------------------------------------------------------------------
// C[M,N] = A[M,K=H] @ W[N,K=H]^T + bias     (both operands K-contiguous, "NT")
// MODE 0: write into head-major (b, h, s, d) layout for Q/K/V
// MODE 1: write plain row-major M x H
// Tile: BM=128, BN=64, BK=16; 256 threads (16x16); 8x4 microtile per thread.
// LDS stores k-major (transposed) so compute reads are float4.
// ---------------------------------------------------------------------------
template<int MODE>
__global__ __launch_bounds__(256)
void gemm_nt(const float* __restrict__ A, const float* __restrict__ W,
             const float* __restrict__ bias, float* __restrict__ out)
{
    __shared__ float As[16][132];   // [k][m] pad: 132*4B = 16-aligned rows, stride%32==4
    __shared__ float Bs[16][68];    // [k][n]

    const int tx = threadIdx.x;     // 0..15
    const int ty = threadIdx.y;     // 0..15
    const int t  = ty * 16 + tx;
    const int m0 = blockIdx.y * 128;
    const int n0 = blockIdx.x * 64;

    const int lr = t >> 2;          // 0..63
    const int lk = (t & 3) << 2;    // 0,4,8,12

    float acc[8][4];
#pragma unroll
    for (int i = 0; i < 8; ++i)
#pragma unroll
        for (int j = 0; j < 4; ++j) acc[i][j] = 0.f;

    const float* pa0 = A + (size_t)(m0 + lr) * H_ + lk;
    const float* pa1 = pa0 + (size_t)64 * H_;
    const float* pw  = W + (size_t)(n0 + lr) * H_ + lk;

    for (int kt = 0; kt < H_; kt += 16) {
        const float4 a0 = *(const float4*)(pa0 + kt);
        const float4 a1 = *(const float4*)(pa1 + kt);
        const float4 w0 = *(const float4*)(pw  + kt);
        __syncthreads();   // protect previous iteration's LDS reads
        As[lk+0][lr]    = a0.x; As[lk+1][lr]    = a0.y; As[lk+2][lr]    = a0.z; As[lk+3][lr]    = a0.w;
        As[lk+0][lr+64] = a1.x; As[lk+1][lr+64] = a1.y; As[lk+2][lr+64] = a1.z; As[lk+3][lr+64] = a1.w;
        Bs[lk+0][lr]    = w0.x; Bs[lk+1][lr]    = w0.y; Bs[lk+2][lr]    = w0.z; Bs[lk+3][lr]    = w0.w;
        __syncthreads();
#pragma unroll
        for (int k = 0; k < 16; ++k) {
            F4 x0, x1, y;
            x0.v = *(const float4*)&As[k][ty*8];
            x1.v = *(const float4*)&As[k][ty*8 + 4];
            y.v  = *(const float4*)&Bs[k][tx*4];
#pragma unroll
            for (int j = 0; j < 4; ++j) {
#pragma unroll
                for (int i = 0; i < 4; ++i) acc[i][j]   = fmaf(x0.f[i], y.f[j], acc[i][j]);
#pragma unroll
                for (int i = 0; i < 4; ++i) acc[i+4][j] = fmaf(x1.f[i], y.f[j], acc[i+4][j]);
            }
        }
    }

    F4 bv; bv.v = *(const float4*)&bias[n0 + tx*4];
#pragma unroll
    for (int i = 0; i < 8; ++i) {
        const int m = m0 + ty*8 + i;
        float4 r;
        r.x = acc[i][0] + bv.f[0];
        r.y = acc[i][1] + bv.f[1];
        r.z = acc[i][2] + bv.f[2];
        r.w = acc[i][3] + bv.f[3];
        if (MODE == 0) {
            const int b = m >> 11;            // m / S_
            const int s = m & (S_ - 1);
            const int h = n0 >> 6;            // 64-aligned tile = exactly one head
            *(float4*)&out[((size_t)(b*NH_ + h) * S_ + s) * HD_ + tx*4] = r;
        } else {
            *(float4*)&out[(size_t)m * H_ + n0 + tx*4] = r;
        }
    }
}

// ---------------------------------------------------------------------------
// RoPE on Q and K, head-major (bh, s, d) layout.  Pairs (d, d+32), d<32.
// q'_d      = q_d*cos[s,d]    - q_{d+32}*sin[s,d]
// q'_{d+32} = q_{d+32}*cos[s,d+32] + q_d*sin[s,d+32]
// ---------------------------------------------------------------------------
__global__ __launch_bounds__(256)
void rope_kernel(float* __restrict__ q, float* __restrict__ k,
                 const float* __restrict__ cb, const float* __restrict__ sb)
{
    const int idx = blockIdx.x * 256 + threadIdx.x;   // over BH*S*32
    const int d  = idx & 31;
    const int s  = (idx >> 5) & (S_ - 1);
    const int bh = idx >> 16;                          // 5 + 11 bits
    const size_t base = ((size_t)bh * S_ + s) * HD_;
    const float c0 = cb[s*HD_ + d];
    const float c1 = cb[s*HD_ + d + 32];
    const float s0 = sb[s*HD_ + d];
    const float s1 = sb[s*HD_ + d + 32];
    const float q0v = q[base + d], q1v = q[base + d + 32];
    q[base + d]      = fmaf(q0v, c0, -q1v * s0);
    q[base + d + 32] = fmaf(q1v, c1,  q0v * s1);
    const float k0v = k[base + d], k1v = k[base + d + 32];
    k[base + d]      = fmaf(k0v, c0, -k1v * s0);
    k[base + d + 32] = fmaf(k1v, c1,  k0v * s1);
}

// ---------------------------------------------------------------------------
// Flash attention (non-causal).  One block = one (b,h) x 64 q-rows.
// 256 threads (16x16); thread owns 4 q-rows x 4 out-cols.
// LDS: Qs/Vs/Ps linear [r][d] stride 64; Ks XOR-swizzled (16B slot ^= row>>2&7)
// because QK^T reads vary the ROW across lanes (else 16-way bank conflict).
// Softmax row-reductions via __shfl_xor over the 16-lane tx group.
// Output written to (b, s, h*64+d) row-major for the O-projection.
// ---------------------------------------------------------------------------
__global__ __launch_bounds__(256)
void attn_kernel(const float* __restrict__ Q, const float* __restrict__ K,
                 const float* __restrict__ V, float* __restrict__ AO)
{
    __shared__ float Qs[64*64];
    __shared__ float Ks[64*64];
    __shared__ float Vs[64*64];
    __shared__ float Ps[64*64];

    const int tx = threadIdx.x, ty = threadIdx.y;
    const int t  = ty * 16 + tx;
    const int bh = blockIdx.y;
    const int q0 = blockIdx.x * 64;

    const float* Qg = Q + ((size_t)bh * S_ + q0) * HD_;
    const float* Kg = K + (size_t)bh * S_ * HD_;
    const float* Vg = V + (size_t)bh * S_ * HD_;

#pragma unroll
    for (int it = 0; it < 4; ++it) {
        const int idx = it*256 + t;
        const int r = idx >> 4, v4 = idx & 15;
        *(float4*)&Qs[r*64 + v4*4] = *(const float4*)(Qg + (size_t)r*HD_ + v4*4);
    }

    float oacc[4][4];
#pragma unroll
    for (int i = 0; i < 4; ++i)
#pragma unroll
        for (int j = 0; j < 4; ++j) oacc[i][j] = 0.f;
    float mrun[4], lrun[4];
#pragma unroll
    for (int i = 0; i < 4; ++i) { mrun[i] = -1e30f; lrun[i] = 0.f; }

    const int r0 = ty * 4;       // q rows of this thread (within tile)
    const int c0 = tx * 4;       // k cols in QK / out cols in PV
    const int sw = tx & 7;       // Ks swizzle for reads: (c>>2)&7 == tx&7

    for (int kt = 0; kt < S_; kt += 64) {
        __syncthreads();   // (a) prev PV reads of Vs/Ps done; safe to overwrite
#pragma unroll
        for (int it = 0; it < 4; ++it) {
            const int idx = it*256 + t;
            const int r = idx >> 4, v4 = idx & 15;
            const float4 kx = *(const float4*)(Kg + (size_t)(kt + r)*HD_ + v4*4);
            const float4 vx = *(const float4*)(Vg + (size_t)(kt + r)*HD_ + v4*4);
            const int sl = v4 ^ ((r >> 2) & 7);
            *(float4*)&Ks[r*64 + sl*4] = kx;
            *(float4*)&Vs[r*64 + v4*4] = vx;
        }
        __syncthreads();   // (b) K,V tiles ready

        float s[4][4];
#pragma unroll
        for (int i = 0; i < 4; ++i)
#pragma unroll
            for (int j = 0; j < 4; ++j) s[i][j] = 0.f;

#pragma unroll
        for (int dc = 0; dc < 16; ++dc) {
            F4 qv[4], kv[4];
#pragma unroll
            for (int i = 0; i < 4; ++i) qv[i].v = *(const float4*)&Qs[(r0+i)*64 + dc*4];
#pragma unroll
            for (int j = 0; j < 4; ++j) kv[j].v = *(const float4*)&Ks[(c0+j)*64 + ((dc ^ sw) << 2)];
#pragma unroll
            for (int i = 0; i < 4; ++i)
#pragma unroll
                for (int j = 0; j < 4; ++j)
#pragma unroll
                    for (int u = 0; u < 4; ++u)
                        s[i][j] = fmaf(qv[i].f[u], kv[j].f[u], s[i][j]);
        }

        // online softmax update
        float p[4][4];
#pragma unroll
        for (int i = 0; i < 4; ++i) {
            float tm = -1e30f;
#pragma unroll
            for (int j = 0; j < 4; ++j) { s[i][j] *= 0.125f; tm = fmaxf(tm, s[i][j]); }
#pragma unroll
            for (int mk = 1; mk < 16; mk <<= 1) tm = fmaxf(tm, __shfl_xor(tm, mk));
            const float mnew  = fmaxf(mrun[i], tm);
            const float alpha = __expf(mrun[i] - mnew);
            float sum = 0.f;
#pragma unroll
            for (int j = 0; j < 4; ++j) { p[i][j] = __expf(s[i][j] - mnew); sum += p[i][j]; }
#pragma unroll
            for (int mk = 1; mk < 16; mk <<= 1) sum += __shfl_xor(sum, mk);
            lrun[i] = lrun[i] * alpha + sum;
            mrun[i] = mnew;
#pragma unroll
            for (int j = 0; j < 4; ++j) oacc[i][j] *= alpha;
        }

#pragma unroll
        for (int i = 0; i < 4; ++i)
            *(float4*)&Ps[(r0+i)*64 + c0] = make_float4(p[i][0], p[i][1], p[i][2], p[i][3]);
        __syncthreads();   // (c) P tile ready

        // PV: oacc[i][j] += sum_k P[r_i][k] * V[k][c_j]
#pragma unroll
        for (int kc = 0; kc < 16; ++kc) {
            F4 pv[4], vv[4];
#pragma unroll
            for (int i = 0; i < 4; ++i) pv[i].v = *(const float4*)&Ps[(r0+i)*64 + kc*4];
#pragma unroll
            for (int u = 0; u < 4; ++u) vv[u].v = *(const float4*)&Vs[(kc*4+u)*64 + c0];
#pragma unroll
            for (int i = 0; i < 4; ++i)
#pragma unroll
                for (int j = 0; j < 4; ++j)
#pragma unroll
                    for (int u = 0; u < 4; ++u)
                        oacc[i][j] = fmaf(pv[i].f[u], vv[u].f[j], oacc[i][j]);
        }
    }

    const int b = bh / NH_, h = bh % NH_;
#pragma unroll
    for (int i = 0; i < 4; ++i) {
        const float inv = 1.f / lrun[i];
        const int srow = q0 + r0 + i;
        const float4 o = make_float4(oacc[i][0]*inv, oacc[i][1]*inv,
                                     oacc[i][2]*inv, oacc[i][3]*inv);
        *(float4*)&AO[((size_t)(b * S_ + srow)) * H_ + h*HD_ + c0] = o;
    }
}

// ---------------------------------------------------------------------------
extern "C" void kernel_launch(void* const* d_in, const int* in_sizes, int n_in,
                              void* d_out, int out_size, void* d_ws, size_t ws_size,
                              hipStream_t stream)
{
    const float* X    = (const float*)d_in[0];
    const float* cosb = (const float*)d_in[1];
    const float* sinb = (const float*)d_in[2];
    const float* wq   = (const float*)d_in[3];
    const float* bq   = (const float*)d_in[4];
    const float* wk   = (const float*)d_in[5];
    const float* bk   = (const float*)d_in[6];
    const float* wv   = (const float*)d_in[7];
    const float* bv   = (const float*)d_in[8];
    const float* wo   = (const float*)d_in[9];
    const float* bo   = (const float*)d_in[10];
    float* out = (float*)d_out;

    // workspace: Q, K, V (head-major), attn-out (row-major) — 4 x 25.2 MB
    float* Qb = (float*)d_ws;
    float* Kb = Qb + (size_t)M_ * H_;
    float* Vb = Kb + (size_t)M_ * H_;
    float* AO = Vb + (size_t)M_ * H_;

    const dim3 blk(16, 16);
    const dim3 gg(H_ / 64, M_ / 128);       // (24, 32)

    gemm_nt<0><<<gg, blk, 0, stream>>>(X, wq, bq, Qb);
    gemm_nt<0><<<gg, blk, 0, stream>>>(X, wk, bk, Kb);
    gemm_nt<0><<<gg, blk, 0, stream>>>(X, wv, bv, Vb);

    rope_kernel<<<(B_*NH_*S_*32)/256, 256, 0, stream>>>(Qb, Kb, cosb, sinb);

    attn_kernel<<<dim3(S_/64, B_*NH_), blk, 0, stream>>>(Qb, Kb, Vb, AO);

    gemm_nt<1><<<gg, blk, 0, stream>>>(AO, wo, bo, out);
}

// Round 2
// 1138.747 us; speedup vs baseline: 1.9885x; 1.9885x over previous
//
#include <hip/hip_runtime.h>
#include <hip/hip_bf16.h>
#include <cstdint>

namespace {
constexpr int H_  = 1536;
constexpr int NH_ = 24;
constexpr int HD_ = 64;
constexpr int B_  = 2;
constexpr int S_  = 2048;
constexpr int M_  = B_ * S_;   // 4096
}

union F4 { float4 v; float f[4]; };

typedef __attribute__((ext_vector_type(8))) short  bf16x8;   // 8 bf16 = 4 VGPR
typedef __attribute__((ext_vector_type(4))) float  f32x4;
typedef __attribute__((ext_vector_type(8))) unsigned short ushort8v;

__device__ __forceinline__ short f2bf(float x) {
    union { __hip_bfloat16 h; short s; } u;
    u.h = __float2bfloat16(x);
    return u.s;
}

// ---------------------------------------------------------------------------
// C[M,N] = A[M,K=H] @ W[N,K=H]^T + bias     (both operands K-contiguous, "NT")
// MODE 0: RoPE + scale + bf16, head-major (b,h,s,d)          (Q and K)
// MODE 1: fp32 row-major M x H                               (O-projection)
// MODE 2: bf16, head-major TRANSPOSED (b,h,d,s)              (V)
// Tile: BM=128, BN=64, BK=16; 256 threads (16x16); 8x4 microtile per thread.
// ---------------------------------------------------------------------------
template<int MODE>
__global__ __launch_bounds__(256)
void gemm_nt(const float* __restrict__ A, const float* __restrict__ W,
             const float* __restrict__ bias, float* __restrict__ outf,
             short* __restrict__ outb,
             const float* __restrict__ cosb, const float* __restrict__ sinb,
             float scale)
{
    __shared__ float As[16][132];
    __shared__ float Bs[16][68];

    const int tx = threadIdx.x;     // 0..15
    const int ty = threadIdx.y;     // 0..15
    const int t  = ty * 16 + tx;
    const int m0 = blockIdx.y * 128;
    const int n0 = blockIdx.x * 64;

    const int lr = t >> 2;          // 0..63
    const int lk = (t & 3) << 2;    // 0,4,8,12

    float acc[8][4];
#pragma unroll
    for (int i = 0; i < 8; ++i)
#pragma unroll
        for (int j = 0; j < 4; ++j) acc[i][j] = 0.f;

    const float* pa0 = A + (size_t)(m0 + lr) * H_ + lk;
    const float* pa1 = pa0 + (size_t)64 * H_;
    const float* pw  = W + (size_t)(n0 + lr) * H_ + lk;

    for (int kt = 0; kt < H_; kt += 16) {
        const float4 a0 = *(const float4*)(pa0 + kt);
        const float4 a1 = *(const float4*)(pa1 + kt);
        const float4 w0 = *(const float4*)(pw  + kt);
        __syncthreads();
        As[lk+0][lr]    = a0.x; As[lk+1][lr]    = a0.y; As[lk+2][lr]    = a0.z; As[lk+3][lr]    = a0.w;
        As[lk+0][lr+64] = a1.x; As[lk+1][lr+64] = a1.y; As[lk+2][lr+64] = a1.z; As[lk+3][lr+64] = a1.w;
        Bs[lk+0][lr]    = w0.x; Bs[lk+1][lr]    = w0.y; Bs[lk+2][lr]    = w0.z; Bs[lk+3][lr]    = w0.w;
        __syncthreads();
#pragma unroll
        for (int k = 0; k < 16; ++k) {
            F4 x0, x1, y;
            x0.v = *(const float4*)&As[k][ty*8];
            x1.v = *(const float4*)&As[k][ty*8 + 4];
            y.v  = *(const float4*)&Bs[k][tx*4];
#pragma unroll
            for (int j = 0; j < 4; ++j) {
#pragma unroll
                for (int i = 0; i < 4; ++i) acc[i][j]   = fmaf(x0.f[i], y.f[j], acc[i][j]);
#pragma unroll
                for (int i = 0; i < 4; ++i) acc[i+4][j] = fmaf(x1.f[i], y.f[j], acc[i+4][j]);
            }
        }
    }

    F4 bv; bv.v = *(const float4*)&bias[n0 + tx*4];
    const int h = n0 >> 6;                 // tile width 64 == one head

    if (MODE == 2) {
        // V: bf16, transposed per-head layout out[(b*NH+h)*64 + d][s]
        const int b  = m0 >> 11;
        const int s0 = (m0 & (S_ - 1)) + ty*8;
#pragma unroll
        for (int j = 0; j < 4; ++j) {
            const int d = tx*4 + j;
            ushort8v u;
#pragma unroll
            for (int i = 0; i < 8; ++i) u[i] = (unsigned short)f2bf(acc[i][j] + bv.f[j]);
            *(ushort8v*)&outb[((size_t)((b*NH_ + h)*HD_ + d)) * S_ + s0] = u;
        }
        return;
    }

#pragma unroll
    for (int i = 0; i < 8; ++i) {
        const int m = m0 + ty*8 + i;
        const int b = m >> 11;
        const int s = m & (S_ - 1);
        float r[4];
#pragma unroll
        for (int j = 0; j < 4; ++j) r[j] = acc[i][j] + bv.f[j];

        if (MODE == 1) {
            *(float4*)&outf[(size_t)m * H_ + n0 + tx*4] = make_float4(r[0], r[1], r[2], r[3]);
        } else {
            // MODE 0: RoPE (pair d <-> d+-32 lives in lane^8) + scale + bf16
            F4 c4, s4;
            c4.v = *(const float4*)&cosb[s*HD_ + tx*4];
            s4.v = *(const float4*)&sinb[s*HD_ + tx*4];
            ushort us[4];
#pragma unroll
            for (int j = 0; j < 4; ++j) {
                const float part = __shfl_xor(r[j], 8);
                const float rot  = (tx < 8) ? -part : part;
                us[j] = (ushort)f2bf((r[j]*c4.f[j] + rot*s4.f[j]) * scale);
            }
            *(ushort4*)&outb[((size_t)((b*NH_ + h)*S_ + s)) * HD_ + tx*4] =
                make_ushort4(us[0], us[1], us[2], us[3]);
        }
    }
}

// ---------------------------------------------------------------------------
// Flash attention, bf16 MFMA (16x16x32), fp32 accum, non-causal.
// Block = 256 thr = 4 waves; wave owns 16 q-rows; block = 64 q-rows; KV tile 64.
// Swapped QK^T: S^T = mfma(K, Q^T) -> softmax reduction is lane-local
// (16 regs + shfl_xor 16/32).  O^T = mfma(V^T, P^T).
// K tile LDS [kv][d], Vt tile LDS [d][kv], both XOR-swizzled (slot ^= row&7)
// since frag reads vary the row across lanes (128B stride = 32-way otherwise).
// P^T staged per-wave in LDS (acc layout -> A-frag layout reshape).
// ---------------------------------------------------------------------------
__global__ __launch_bounds__(256)
void attn_mfma(const short* __restrict__ Q, const short* __restrict__ K,
               const short* __restrict__ Vt, float* __restrict__ AO)
{
    __shared__ short Ks[64*64];      // [kv][d] swizzled, 8 KB
    __shared__ short Vs[64*64];      // [d][kv] swizzled, 8 KB
    __shared__ short Ps[4][16*64];   // per-wave [q][kv] swizzled, 8 KB

    const int t    = threadIdx.x;
    const int lane = t & 63;
    const int wid  = t >> 6;
    const int bh   = blockIdx.y;
    const int q0   = blockIdx.x * 64;

    const int l15 = lane & 15;       // q (B-frag col / C col)  or kv-row base
    const int grp = lane >> 4;       // k-block selector
    const int sw  = lane & 7;        // swizzle key (== row&7 for our rows)

    const short* Qg = Q  + ((size_t)bh * S_ + q0 + wid*16) * HD_;
    const short* Kg = K  + (size_t)bh * S_ * HD_;
    const short* Vg = Vt + (size_t)bh * HD_ * S_;

    // Q fragments (B-operand of swapped QK^T): lane holds Q[q=l15][d=grp*8+j+f*32]
    bf16x8 qf[2];
#pragma unroll
    for (int f = 0; f < 2; ++f)
        qf[f] = *(const bf16x8*)(Qg + (size_t)l15*HD_ + f*32 + grp*8);

    f32x4 oacc[4];                   // O^T[d = nt*16+grp*4+r][q = l15]
#pragma unroll
    for (int nt = 0; nt < 4; ++nt) oacc[nt] = (f32x4){0.f,0.f,0.f,0.f};
    float mrun = -1e30f, lrun = 0.f; // per q-col (dup x4 across lane groups)

    for (int kt = 0; kt < S_; kt += 64) {
        __syncthreads();             // prior tile's Ks/Vs reads complete
#pragma unroll
        for (int half = 0; half < 2; ++half) {
            const int c = half*256 + t;
            const int row = c >> 3, slot = c & 7;
            const int didx = row*64 + ((slot ^ (row & 7)) << 3);
            *(float4*)&Ks[didx] = *(const float4*)(Kg + (size_t)(kt + row)*HD_ + slot*8);
            *(float4*)&Vs[didx] = *(const float4*)(Vg + (size_t)row*S_ + kt + slot*8);
        }
        __syncthreads();

        // S^T = K * Q^T   (A = K tile rows kv, B = Q^T)
        f32x4 sac[4];
#pragma unroll
        for (int nt = 0; nt < 4; ++nt) sac[nt] = (f32x4){0.f,0.f,0.f,0.f};
#pragma unroll
        for (int f = 0; f < 2; ++f) {
            const int slotf = ((grp + f*4) ^ sw) << 3;
#pragma unroll
            for (int nt = 0; nt < 4; ++nt) {
                const bf16x8 kfrag = *(const bf16x8*)&Ks[(nt*16 + l15)*64 + slotf];
                sac[nt] = __builtin_amdgcn_mfma_f32_16x16x32_bf16(kfrag, qf[f], sac[nt], 0, 0, 0);
            }
        }

        // online softmax over kv (lane-local 16 + shfl 16,32)
        float tm = sac[0][0];
#pragma unroll
        for (int nt = 0; nt < 4; ++nt)
#pragma unroll
            for (int r = 0; r < 4; ++r) tm = fmaxf(tm, sac[nt][r]);
        tm = fmaxf(tm, __shfl_xor(tm, 16));
        tm = fmaxf(tm, __shfl_xor(tm, 32));
        const float mnew  = fmaxf(mrun, tm);
        const float alpha = __expf(mrun - mnew);
        float psum = 0.f;
#pragma unroll
        for (int nt = 0; nt < 4; ++nt)
#pragma unroll
            for (int r = 0; r < 4; ++r) {
                sac[nt][r] = __expf(sac[nt][r] - mnew);
                psum += sac[nt][r];
            }
        psum += __shfl_xor(psum, 16);
        psum += __shfl_xor(psum, 32);
        lrun = lrun * alpha + psum;
        mrun = mnew;
#pragma unroll
        for (int nt = 0; nt < 4; ++nt)
#pragma unroll
            for (int r = 0; r < 4; ++r) oacc[nt][r] *= alpha;

        // P^T -> per-wave LDS, bf16, [q][kv] with slot ^= q&7
#pragma unroll
        for (int nt = 0; nt < 4; ++nt)
#pragma unroll
            for (int r = 0; r < 4; ++r) {
                const int kv  = nt*16 + grp*4 + r;
                const int idx = l15*64 + (((kv >> 3) ^ sw) << 3) + (kv & 7);
                Ps[wid][idx] = f2bf(sac[nt][r]);
            }

        // O^T += V^T * P^T   (A = V^T rows d, B = P^T)
#pragma unroll
        for (int f = 0; f < 2; ++f) {
            const int slotf = ((grp + f*4) ^ sw) << 3;
            const bf16x8 pfrag = *(const bf16x8*)&Ps[wid][l15*64 + slotf];
#pragma unroll
            for (int nt = 0; nt < 4; ++nt) {
                const bf16x8 vfrag = *(const bf16x8*)&Vs[(nt*16 + l15)*64 + slotf];
                oacc[nt] = __builtin_amdgcn_mfma_f32_16x16x32_bf16(vfrag, pfrag, oacc[nt], 0, 0, 0);
            }
        }
    }

    // epilogue: O = O^T / lrun, scatter to AO fp32 [b*S+s][h*64+d]
    const float inv = 1.f / lrun;
    const int b = bh / NH_, h = bh % NH_;
    const int srow = q0 + wid*16 + l15;
    float* dst = AO + ((size_t)(b*S_ + srow)) * H_ + h*HD_;
#pragma unroll
    for (int nt = 0; nt < 4; ++nt)
#pragma unroll
        for (int r = 0; r < 4; ++r)
            dst[nt*16 + grp*4 + r] = oacc[nt][r] * inv;
}

// ---------------------------------------------------------------------------
extern "C" void kernel_launch(void* const* d_in, const int* in_sizes, int n_in,
                              void* d_out, int out_size, void* d_ws, size_t ws_size,
                              hipStream_t stream)
{
    const float* X    = (const float*)d_in[0];
    const float* cosb = (const float*)d_in[1];
    const float* sinb = (const float*)d_in[2];
    const float* wq   = (const float*)d_in[3];
    const float* bq   = (const float*)d_in[4];
    const float* wk   = (const float*)d_in[5];
    const float* bk   = (const float*)d_in[6];
    const float* wv   = (const float*)d_in[7];
    const float* bv   = (const float*)d_in[8];
    const float* wo   = (const float*)d_in[9];
    const float* bo   = (const float*)d_in[10];
    float* out = (float*)d_out;

    // workspace: Qb16, Kb16, Vt16 (bf16 head-major; V transposed) + AO (fp32)
    short* Qb = (short*)d_ws;
    short* Kb = Qb + (size_t)M_ * H_;
    short* Vb = Kb + (size_t)M_ * H_;
    float* AO = (float*)(Vb + (size_t)M_ * H_);

    const dim3 blk(16, 16);
    const dim3 gg(H_ / 64, M_ / 128);       // (24, 32)

    gemm_nt<0><<<gg, blk, 0, stream>>>(X, wq, bq, nullptr, Qb, cosb, sinb, 0.125f);
    gemm_nt<0><<<gg, blk, 0, stream>>>(X, wk, bk, nullptr, Kb, cosb, sinb, 1.0f);
    gemm_nt<2><<<gg, blk, 0, stream>>>(X, wv, bv, nullptr, Vb, nullptr, nullptr, 1.0f);

    attn_mfma<<<dim3(S_/64, B_*NH_), 256, 0, stream>>>(Qb, Kb, Vb, AO);

    gemm_nt<1><<<gg, blk, 0, stream>>>(AO, wo, bo, out, nullptr, nullptr, nullptr, 1.0f);
}

// Round 3
// 387.366 us; speedup vs baseline: 5.8455x; 2.9397x over previous
//
#include <hip/hip_runtime.h>
#include <hip/hip_bf16.h>
#include <cstdint>

namespace {
constexpr int H_  = 1536;
constexpr int NH_ = 24;
constexpr int HD_ = 64;
constexpr int B_  = 2;
constexpr int S_  = 2048;
constexpr int M_  = B_ * S_;          // 4096
constexpr int KD_ = H_;               // GEMM depth
}

typedef __attribute__((ext_vector_type(8))) short  bf16x8;
typedef __attribute__((ext_vector_type(4))) float  f32x4;

__device__ __forceinline__ short f2bf(float x) {
    union { __hip_bfloat16 h; short s; } u;
    u.h = __float2bfloat16(x);
    return u.s;
}
__device__ __forceinline__ float bf2f(short s) {
    union { __hip_bfloat16 h; short s; } u;
    u.s = s;
    return __bfloat162float(u.h);
}

__device__ __forceinline__ void gload16(const short* g, short* l) {
    __builtin_amdgcn_global_load_lds(
        (const __attribute__((address_space(1))) unsigned int*)g,
        (__attribute__((address_space(3))) unsigned int*)l, 16, 0, 0);
}

// ---------------------------------------------------------------------------
// split fp32 -> (hi, lo) bf16;  x = hi + lo to ~16 mantissa bits
// ---------------------------------------------------------------------------
__global__ __launch_bounds__(256)
void split_f32(const float* __restrict__ x, short* __restrict__ hi,
               short* __restrict__ lo, int n)
{
    const int i = (blockIdx.x * 256 + threadIdx.x) * 4;
    if (i >= n) return;
    const float4 v = *(const float4*)&x[i];
    ushort4 h, l;
    const float f[4] = {v.x, v.y, v.z, v.w};
    unsigned short hh[4], ll[4];
#pragma unroll
    for (int j = 0; j < 4; ++j) {
        const short hs = f2bf(f[j]);
        hh[j] = (unsigned short)hs;
        ll[j] = (unsigned short)f2bf(f[j] - bf2f(hs));
    }
    h = make_ushort4(hh[0], hh[1], hh[2], hh[3]);
    l = make_ushort4(ll[0], ll[1], ll[2], ll[3]);
    *(ushort4*)&hi[i] = h;
    *(ushort4*)&lo[i] = l;
}

// ---------------------------------------------------------------------------
// Split-bf16 GEMM:  C[M,N] = (Ahi+Alo)[M,K] @ (Bhi+Blo)[N,K]^T + bias
// via 3 MFMA passes (hi*hi + hi*lo + lo*hi), fp32 accum.
// Tile 128x128, BK=64, 256 thr = 4 waves (2x2), wave = 64x64 = 4x4 frags of
// 16x16x32.  Staging: global_load_lds w16, source pre-swizzled; LDS reads
// XOR-swizzled (slot ^= row&7) -> conflict-free ds_read_b128.
// KIND 0 (QKV fused, grid 1152): z=0 Q (rope+0.125), z=1 K (rope), z=2 V
// (bf16 transposed (b,h,d,s)).  KIND 1 (O-proj, grid 384): fp32 out + bias.
// Bijective XCD swizzle: m-tile determined by bid&7 -> A-tile stays in XCD L2.
// ---------------------------------------------------------------------------
template<int KIND>
__global__ __launch_bounds__(256, 2)
void gemm_split(const short* __restrict__ Ahi_g, const short* __restrict__ Alo_g,
                const short* __restrict__ Wqh, const short* __restrict__ Wql,
                const short* __restrict__ Wkh, const short* __restrict__ Wkl,
                const short* __restrict__ Wvh, const short* __restrict__ Wvl,
                const float* __restrict__ bq, const float* __restrict__ bk,
                const float* __restrict__ bv,
                const float* __restrict__ cosb, const float* __restrict__ sinb,
                short* __restrict__ Qb, short* __restrict__ Kb,
                short* __restrict__ Vt, float* __restrict__ outf)
{
    __shared__ short Ah[128*64], Al[128*64], Bh[128*64], Bl[128*64]; // 16KB ea

    const int t    = threadIdx.x;
    const int lane = t & 63;
    const int w    = t >> 6;
    const int wr   = w >> 1, wc = w & 1;
    const int l15  = lane & 15;
    const int grp  = lane >> 4;

    // bijective XCD-aware decode: m fast (4 per XCD), then n, then z
    const int xcd = blockIdx.x & 7;
    const int off = blockIdx.x >> 3;
    const int m_idx = xcd * 4 + (off & 3);
    const int rest  = off >> 2;                  // QKV: 0..35, O: 0..11
    const int n_idx = rest % 12;
    const int zi    = (KIND == 0) ? rest / 12 : 3;

    const int m0 = m_idx * 128;
    const int n0 = n_idx * 128;

    const short* bhg; const short* blg; const float* bias;
    if (KIND == 0) {
        if      (zi == 0) { bhg = Wqh; blg = Wql; bias = bq; }
        else if (zi == 1) { bhg = Wkh; blg = Wkl; bias = bk; }
        else              { bhg = Wvh; blg = Wvl; bias = bv; }
    } else {
        bhg = Wqh; blg = Wql; bias = bq;         // O-proj passes wo/bo here
    }

    f32x4 acc[4][4];
#pragma unroll
    for (int i = 0; i < 4; ++i)
#pragma unroll
        for (int j = 0; j < 4; ++j) acc[i][j] = (f32x4){0.f, 0.f, 0.f, 0.f};

    // staging geometry: chunk = 1KB = 8 rows x 8 slots(16B); wave w stages
    // chunks w*4..w*4+3 of each array; lane -> row r0+(l>>3), phys slot l&7,
    // global slot (l&7)^(l>>3)  (pre-swizzled source, rule 21)
    const int srow = lane >> 3;
    const int sslot = (lane & 7) ^ srow;

    for (int kt = 0; kt < KD_; kt += 64) {
        __syncthreads();
#pragma unroll
        for (int cc = 0; cc < 4; ++cc) {
            const int c = w * 4 + cc;
            const int r = c * 8 + srow;
            const size_t aoff = (size_t)(m0 + r) * KD_ + kt + sslot * 8;
            const size_t boff = (size_t)(n0 + r) * KD_ + kt + sslot * 8;
            gload16(Ahi_g + aoff, Ah + c * 512);
            gload16(Alo_g + aoff, Al + c * 512);
            gload16(bhg  + boff, Bh + c * 512);
            gload16(blg  + boff, Bl + c * 512);
        }
        __syncthreads();

#pragma unroll
        for (int kk = 0; kk < 2; ++kk) {
            bf16x8 af[4][2], bf[4][2];
#pragma unroll
            for (int i = 0; i < 4; ++i) {
                const int ra = wr * 64 + i * 16 + l15;
                const int sa = ((kk * 4 + grp) ^ (ra & 7)) * 8;
                af[i][0] = *(const bf16x8*)&Ah[ra * 64 + sa];
                af[i][1] = *(const bf16x8*)&Al[ra * 64 + sa];
                const int rb = wc * 64 + i * 16 + l15;
                const int sb = ((kk * 4 + grp) ^ (rb & 7)) * 8;
                bf[i][0] = *(const bf16x8*)&Bh[rb * 64 + sb];
                bf[i][1] = *(const bf16x8*)&Bl[rb * 64 + sb];
            }
#pragma unroll
            for (int i = 0; i < 4; ++i)
#pragma unroll
                for (int j = 0; j < 4; ++j)
                    acc[i][j] = __builtin_amdgcn_mfma_f32_16x16x32_bf16(af[i][0], bf[j][0], acc[i][j], 0, 0, 0);
#pragma unroll
            for (int i = 0; i < 4; ++i)
#pragma unroll
                for (int j = 0; j < 4; ++j)
                    acc[i][j] = __builtin_amdgcn_mfma_f32_16x16x32_bf16(af[i][0], bf[j][1], acc[i][j], 0, 0, 0);
#pragma unroll
            for (int i = 0; i < 4; ++i)
#pragma unroll
                for (int j = 0; j < 4; ++j)
                    acc[i][j] = __builtin_amdgcn_mfma_f32_16x16x32_bf16(af[i][1], bf[j][0], acc[i][j], 0, 0, 0);
        }
    }

    // ---------------- epilogue ----------------
    float bn[4];
#pragma unroll
    for (int ni = 0; ni < 4; ++ni) bn[ni] = bias[n0 + wc * 64 + ni * 16 + l15];
    const int hw = (n0 + wc * 64) >> 6;          // head (tile 64-aligned)

    if (KIND == 1) {
#pragma unroll
        for (int mi = 0; mi < 4; ++mi)
#pragma unroll
            for (int r = 0; r < 4; ++r) {
                const int m = m0 + wr * 64 + mi * 16 + grp * 4 + r;
#pragma unroll
                for (int ni = 0; ni < 4; ++ni)
                    outf[(size_t)m * H_ + n0 + wc * 64 + ni * 16 + l15] =
                        acc[mi][ni][r] + bn[ni];
            }
        return;
    }

    if (zi == 2) {
        // V: bf16 transposed (b, h, d, s)
        const int b = m0 >> 11;
#pragma unroll
        for (int mi = 0; mi < 4; ++mi) {
            const int sb = (m0 & (S_ - 1)) + wr * 64 + mi * 16 + grp * 4;
#pragma unroll
            for (int ni = 0; ni < 4; ++ni) {
                const int d = ni * 16 + l15;
                unsigned short u[4];
#pragma unroll
                for (int r = 0; r < 4; ++r)
                    u[r] = (unsigned short)f2bf(acc[mi][ni][r] + bn[ni]);
                *(ushort4*)&Vt[((size_t)(b * NH_ + hw) * HD_ + d) * S_ + sb] =
                    make_ushort4(u[0], u[1], u[2], u[3]);
            }
        }
        return;
    }

    // Q/K: rope + scale + bf16 head-major (b,h,s,d); partner d^32 = acc[..][ni^2]
    const float sc = (zi == 0) ? 0.125f : 1.0f;
    short* dst = (zi == 0) ? Qb : Kb;
#pragma unroll
    for (int mi = 0; mi < 4; ++mi)
#pragma unroll
        for (int r = 0; r < 4; ++r) {
            const int m = m0 + wr * 64 + mi * 16 + grp * 4 + r;
            const int b = m >> 11;
            const int s = m & (S_ - 1);
#pragma unroll
            for (int ni = 0; ni < 4; ++ni) {
                const int d  = ni * 16 + l15;
                const float val = acc[mi][ni][r] + bn[ni];
                const float pv  = acc[mi][ni ^ 2][r] + bn[ni ^ 2];
                const float cs = cosb[s * HD_ + d];
                const float sn = sinb[s * HD_ + d];
                const float rot = (ni < 2) ? -pv : pv;
                dst[((size_t)(b * NH_ + hw) * S_ + s) * HD_ + d] =
                    f2bf((val * cs + rot * sn) * sc);
            }
        }
}

// ---------------------------------------------------------------------------
// Flash attention, bf16 MFMA (16x16x32), fp32 accum.  (unchanged structure;
// epilogue now emits hi/lo bf16 for the split O-projection)
// ---------------------------------------------------------------------------
__global__ __launch_bounds__(256)
void attn_mfma(const short* __restrict__ Q, const short* __restrict__ K,
               const short* __restrict__ Vt,
               short* __restrict__ AOhi, short* __restrict__ AOlo)
{
    __shared__ short Ks[64*64];
    __shared__ short Vs[64*64];
    __shared__ short Ps[4][16*64];

    const int t    = threadIdx.x;
    const int lane = t & 63;
    const int wid  = t >> 6;
    const int bh   = blockIdx.y;
    const int q0   = blockIdx.x * 64;

    const int l15 = lane & 15;
    const int grp = lane >> 4;
    const int sw  = lane & 7;

    const short* Qg = Q  + ((size_t)bh * S_ + q0 + wid*16) * HD_;
    const short* Kg = K  + (size_t)bh * S_ * HD_;
    const short* Vg = Vt + (size_t)bh * HD_ * S_;

    bf16x8 qf[2];
#pragma unroll
    for (int f = 0; f < 2; ++f)
        qf[f] = *(const bf16x8*)(Qg + (size_t)l15*HD_ + f*32 + grp*8);

    f32x4 oacc[4];
#pragma unroll
    for (int nt = 0; nt < 4; ++nt) oacc[nt] = (f32x4){0.f,0.f,0.f,0.f};
    float mrun = -1e30f, lrun = 0.f;

    for (int kt = 0; kt < S_; kt += 64) {
        __syncthreads();
#pragma unroll
        for (int half = 0; half < 2; ++half) {
            const int c = half*256 + t;
            const int row = c >> 3, slot = c & 7;
            const int didx = row*64 + ((slot ^ (row & 7)) << 3);
            *(float4*)&Ks[didx] = *(const float4*)(Kg + (size_t)(kt + row)*HD_ + slot*8);
            *(float4*)&Vs[didx] = *(const float4*)(Vg + (size_t)row*S_ + kt + slot*8);
        }
        __syncthreads();

        f32x4 sac[4];
#pragma unroll
        for (int nt = 0; nt < 4; ++nt) sac[nt] = (f32x4){0.f,0.f,0.f,0.f};
#pragma unroll
        for (int f = 0; f < 2; ++f) {
            const int slotf = ((grp + f*4) ^ sw) << 3;
#pragma unroll
            for (int nt = 0; nt < 4; ++nt) {
                const bf16x8 kfrag = *(const bf16x8*)&Ks[(nt*16 + l15)*64 + slotf];
                sac[nt] = __builtin_amdgcn_mfma_f32_16x16x32_bf16(kfrag, qf[f], sac[nt], 0, 0, 0);
            }
        }

        float tm = sac[0][0];
#pragma unroll
        for (int nt = 0; nt < 4; ++nt)
#pragma unroll
            for (int r = 0; r < 4; ++r) tm = fmaxf(tm, sac[nt][r]);
        tm = fmaxf(tm, __shfl_xor(tm, 16));
        tm = fmaxf(tm, __shfl_xor(tm, 32));
        const float mnew  = fmaxf(mrun, tm);
        const float alpha = __expf(mrun - mnew);
        float psum = 0.f;
#pragma unroll
        for (int nt = 0; nt < 4; ++nt)
#pragma unroll
            for (int r = 0; r < 4; ++r) {
                sac[nt][r] = __expf(sac[nt][r] - mnew);
                psum += sac[nt][r];
            }
        psum += __shfl_xor(psum, 16);
        psum += __shfl_xor(psum, 32);
        lrun = lrun * alpha + psum;
        mrun = mnew;
#pragma unroll
        for (int nt = 0; nt < 4; ++nt)
#pragma unroll
            for (int r = 0; r < 4; ++r) oacc[nt][r] *= alpha;

#pragma unroll
        for (int nt = 0; nt < 4; ++nt)
#pragma unroll
            for (int r = 0; r < 4; ++r) {
                const int kv  = nt*16 + grp*4 + r;
                const int idx = l15*64 + (((kv >> 3) ^ sw) << 3) + (kv & 7);
                Ps[wid][idx] = f2bf(sac[nt][r]);
            }

#pragma unroll
        for (int f = 0; f < 2; ++f) {
            const int slotf = ((grp + f*4) ^ sw) << 3;
            const bf16x8 pfrag = *(const bf16x8*)&Ps[wid][l15*64 + slotf];
#pragma unroll
            for (int nt = 0; nt < 4; ++nt) {
                const bf16x8 vfrag = *(const bf16x8*)&Vs[(nt*16 + l15)*64 + slotf];
                oacc[nt] = __builtin_amdgcn_mfma_f32_16x16x32_bf16(vfrag, pfrag, oacc[nt], 0, 0, 0);
            }
        }
    }

    const float inv = 1.f / lrun;
    const int b = bh / NH_, h = bh % NH_;
    const int srow = q0 + wid*16 + l15;
    const size_t rowb = ((size_t)(b*S_ + srow)) * H_ + h*HD_;
#pragma unroll
    for (int nt = 0; nt < 4; ++nt) {
        unsigned short uh[4], ul[4];
#pragma unroll
        for (int r = 0; r < 4; ++r) {
            const float v = oacc[nt][r] * inv;
            const short hs = f2bf(v);
            uh[r] = (unsigned short)hs;
            ul[r] = (unsigned short)f2bf(v - bf2f(hs));
        }
        *(ushort4*)&AOhi[rowb + nt*16 + grp*4] = make_ushort4(uh[0], uh[1], uh[2], uh[3]);
        *(ushort4*)&AOlo[rowb + nt*16 + grp*4] = make_ushort4(ul[0], ul[1], ul[2], ul[3]);
    }
}

// ---------------------------------------------------------------------------
extern "C" void kernel_launch(void* const* d_in, const int* in_sizes, int n_in,
                              void* d_out, int out_size, void* d_ws, size_t ws_size,
                              hipStream_t stream)
{
    const float* X    = (const float*)d_in[0];
    const float* cosb = (const float*)d_in[1];
    const float* sinb = (const float*)d_in[2];
    const float* wq   = (const float*)d_in[3];
    const float* bq   = (const float*)d_in[4];
    const float* wk   = (const float*)d_in[5];
    const float* bk   = (const float*)d_in[6];
    const float* wv   = (const float*)d_in[7];
    const float* bv   = (const float*)d_in[8];
    const float* wo   = (const float*)d_in[9];
    const float* bo   = (const float*)d_in[10];
    float* out = (float*)d_out;

    const size_t MH = (size_t)M_ * H_;      // 6.29M
    const size_t HH = (size_t)H_ * H_;      // 2.36M

    short* Xhi = (short*)d_ws;
    short* Xlo = Xhi + MH;
    short* Wqh = Xlo + MH;
    short* Wql = Wqh + HH;
    short* Wkh = Wql + HH;
    short* Wkl = Wkh + HH;
    short* Wvh = Wkl + HH;
    short* Wvl = Wvh + HH;
    short* Woh = Wvl + HH;
    short* Wol = Woh + HH;
    short* Qb  = Wol + HH;
    short* Kb  = Qb + MH;
    short* Vt  = Kb + MH;
    short* AOhi = Xhi;                      // X splits dead after QKV GEMM
    short* AOlo = Xlo;

    split_f32<<<(int)(MH/4/256), 256, 0, stream>>>(X,  Xhi, Xlo, (int)MH);
    split_f32<<<(int)(HH/4/256), 256, 0, stream>>>(wq, Wqh, Wql, (int)HH);
    split_f32<<<(int)(HH/4/256), 256, 0, stream>>>(wk, Wkh, Wkl, (int)HH);
    split_f32<<<(int)(HH/4/256), 256, 0, stream>>>(wv, Wvh, Wvl, (int)HH);
    split_f32<<<(int)(HH/4/256), 256, 0, stream>>>(wo, Woh, Wol, (int)HH);

    gemm_split<0><<<1152, 256, 0, stream>>>(Xhi, Xlo,
        Wqh, Wql, Wkh, Wkl, Wvh, Wvl, bq, bk, bv,
        cosb, sinb, Qb, Kb, Vt, nullptr);

    attn_mfma<<<dim3(S_/64, B_*NH_), 256, 0, stream>>>(Qb, Kb, Vt, AOhi, AOlo);

    gemm_split<1><<<384, 256, 0, stream>>>(AOhi, AOlo,
        Woh, Wol, nullptr, nullptr, nullptr, nullptr, bo, nullptr, nullptr,
        nullptr, nullptr, nullptr, nullptr, nullptr, out);
}